// Round 1
// baseline (397.260 us; speedup 1.0000x reference)
//
#include <hip/hip_runtime.h>
#include <hip/hip_bf16.h>
#include <math.h>

// pool_cross on MI355X — round 8.
// k_conv3 rewritten as a pipelined, double-buffered 512-thread kernel:
//   - block = 4 y-rows x 128co x 128x, wave = 1 y-row x 64co x 128x (acc 4x8)
//   - grid 32x2x4 = 256 blocks = exactly 1 block/CU (LDS 118.8 KB)
//   - LDS dbuf: stage(step+1) issued DURING step's 3 compute phases
//     (per kx tap: ds_read frags -> issue stage chunks -> s_barrier ->
//      setprio(1) -> 32 MFMA -> setprio(0) -> s_barrier), vmcnt drained
//     only at step end (T3/T4 minimum pipeline; m97 2-barrier stall was
//     the diagnosed 42%-MfmaUtil cap).
//   - swizzle (slot = c ^ ((row>>1)&3)) and fragment math unchanged from
//     the proven round-7 kernel.
// Other kernels unchanged.
//
// pool algebra (verified): bottom(top(a)) = colmax bcast, right(left(a)) =
// rowmax bcast; merge conv input is rank-1 -> 1-D k_uv decomposition.
// Pool maxes via atomicMax on fp32 bits (valid: values >= 0 post-relu).

constexpr int NB   = 4;
constexpr int CDIM = 256;
constexpr int CMID = 128;
constexpr int HS   = 128;
constexpr int WS   = 128;
constexpr float EPS = 1e-5f;

typedef __bf16 bf16x8 __attribute__((ext_vector_type(8)));
typedef float  f32x4  __attribute__((ext_vector_type(4)));

#define AS1 __attribute__((address_space(1)))
#define AS3 __attribute__((address_space(3)))

__device__ __forceinline__ void load16_lds(const void* gsrc, void* ldst) {
    __builtin_amdgcn_global_load_lds((const AS1 unsigned int*)gsrc,
                                     (AS3 unsigned int*)ldst, 16, 0, 0);
}

// ---------------------------------------------------------------------------
// P0: x[b][ci][y][x] fp32 -> Xc[b][y][x][ci] bf16. Single pass, 512 threads.
__global__ __launch_bounds__(512) void k_xprep(const float* __restrict__ xin,
                                               __hip_bfloat16* __restrict__ Xc)
{
    const int y = blockIdx.x;
    const int b = blockIdx.y;
    const int t = threadIdx.x;
    __shared__ __hip_bfloat16 lds[128 * 264];   // [x][ci], ci-dim padded to 264
#pragma unroll
    for (int k = 0; k < 16; ++k) {
        int idx = t + k * 512;            // 0..8191
        int ci = idx >> 5, x4 = idx & 31;
        f32x4 v = *(const f32x4*)(xin + (((size_t)b * CDIM + ci) * HS + y) * WS + x4 * 4);
#pragma unroll
        for (int j = 0; j < 4; ++j)
            lds[(x4 * 4 + j) * 264 + ci] = __float2bfloat16(v[j]);
    }
    __syncthreads();
#pragma unroll
    for (int k = 0; k < 8; ++k) {
        int i = t + k * 512;              // 0..4095 chunks of 16B
        int x = i >> 5, c8 = i & 31;
        bf16x8 vv = *(const bf16x8*)(lds + x * 264 + c8 * 8);
        *(bf16x8*)(Xc + ((size_t)(b * 128 + y) * 128 + x) * 256 + c8 * 8) = vv;
    }
}

// ---------------------------------------------------------------------------
// All weight preps + zero-fill in one kernel.
// bid 0..127: Aw1; 128..255: Aw2; 256..511: Aw5; 512..639: Aw4 (1x1);
// bid 640..767: zero 4KB each of the cmax|rmax|zbuf region; 768: tail 256B.
__global__ __launch_bounds__(256) void k_wprep_all(
    const float* __restrict__ p1w, const float* __restrict__ p2w,
    const float* __restrict__ c2w, const float* __restrict__ c1w,
    __hip_bfloat16* __restrict__ Aw1, __hip_bfloat16* __restrict__ Aw2,
    __hip_bfloat16* __restrict__ Aw5, __hip_bfloat16* __restrict__ Aw4,
    f32x4* __restrict__ zdst)
{
    const int bid = blockIdx.x;
    const int t   = threadIdx.x;
    if (bid < 512) {
        const float* W; __hip_bfloat16* A; int co;
        if (bid < 128)      { W = p1w; A = Aw1; co = bid; }
        else if (bid < 256) { W = p2w; A = Aw2; co = bid - 128; }
        else                { W = c2w; A = Aw5; co = bid - 256; }
#pragma unroll
        for (int tap = 0; tap < 9; ++tap)
            A[(size_t)co * 2304 + tap * 256 + t] =
                __float2bfloat16(W[((size_t)co * CDIM + t) * 9 + tap]);
    } else if (bid < 640) {
        int base = (bid - 512) * 512 + t;
        Aw4[base]       = __float2bfloat16(c1w[base]);
        Aw4[base + 256] = __float2bfloat16(c1w[base + 256]);
    } else if (bid < 768) {
        zdst[(size_t)(bid - 640) * 256 + t] = (f32x4){0.f, 0.f, 0.f, 0.f};
    } else {
        if (t < 16) zdst[32768 + t] = (f32x4){0.f, 0.f, 0.f, 0.f};
    }
}

// ---------------------------------------------------------------------------
// Conv3x3 implicit GEMM v3: pipelined double-buffered schedule.
// Block: 4 y-rows x 128co x 128x; 8 waves, wave = (yy = w>>1) x (co-half =
// w&1). 24 K-steps of (ky, cih=32ci). Per step: 3 phases (kx taps), each
// {ds_read 12 frags, issue ~3 next-step stage slots, s_barrier, setprio(1),
// 32 MFMA, setprio(0), s_barrier}; one __syncthreads per step drains own
// prefetch (issued >=1 phase earlier).
// MODE 0: plain fp32 NCHW store (K5, blockIdx.y = co-tile). MODE 1: fused
// branches: blockIdx.y==0 -> colmax (LDS colred fold + atomics), ==1 ->
// rowmax (LDS s_red fold + atomics).
template<int MODE>
__global__ __launch_bounds__(512, 2) void k_conv3(
    const __hip_bfloat16* __restrict__ Xc,
    const __hip_bfloat16* __restrict__ AwA, const __hip_bfloat16* __restrict__ AwB,
    const float* __restrict__ zbuf,
    const float* __restrict__ g1, const float* __restrict__ b1,
    const float* __restrict__ m1, const float* __restrict__ v1,
    const float* __restrict__ g2, const float* __restrict__ b2,
    const float* __restrict__ m2, const float* __restrict__ v2,
    float* __restrict__ out0, unsigned* __restrict__ cmax,
    unsigned* __restrict__ rmax, int CO)
{
    const int y0     = blockIdx.x * 4;
    const int branch = blockIdx.y;              // MODE1: branch; MODE0: co-tile
    const int b      = blockIdx.z;
    const int co0    = (MODE == 0) ? branch * 128 : 0;

    const __hip_bfloat16* Aw = (MODE == 1 && branch) ? AwB : AwA;
    const float* gg  = (MODE == 1 && branch) ? g2 : g1;
    const float* bbp = (MODE == 1 && branch) ? b2 : b1;
    const float* mmp = (MODE == 1 && branch) ? m2 : m1;
    const float* vvp = (MODE == 1 && branch) ? v2 : v1;

    // buffer: 904 rows x 64B = 384 A rows (3kx x 128co) + 520 B rows (4y x 130x)
    constexpr int BUFB = 904 * 64;              // 57,856 B
    __shared__ alignas(16) char smb[2 * BUFB];  // 115,712 B
    __shared__ float s_sc[128], s_sh[128];
    __shared__ unsigned s_red[4][128];

    const int t    = threadIdx.x;
    const int lane = t & 63;
    const int w    = t >> 6;
    const int ml   = lane & 15;
    const int q    = lane >> 4;
    const int yy    = w >> 1;                   // wave's y-row 0..3
    const int mbase = (w & 1) * 64;             // wave's co half

    if (t < 128) {
        int co = co0 + t;
        float iv = rsqrtf(vvp[co] + EPS);
        float sc = gg[co] * iv;
        s_sc[t] = sc;
        s_sh[t] = bbp[co] - mmp[co] * sc;
    }
    if (MODE == 1 && branch == 1) ((unsigned*)s_red)[t] = 0u;

    f32x4 acc[4][8];
#pragma unroll
    for (int mt = 0; mt < 4; ++mt)
#pragma unroll
        for (int nt = 0; nt < 8; ++nt)
            acc[mt][nt] = (f32x4){0.f, 0.f, 0.f, 0.f};

    const __hip_bfloat16* bbase = Xc + (size_t)(b * 128) * 128 * 256;

    // stage one 512-thread slot of step (nky,ncih) into dst buffer.
    // 3616 chunks of 16B total (904 rows x 4 slots); slot sl holds logical
    // chunk sl ^ ((row>>1)&3).
    auto stage_slot = [&](int p, int nky, int ncih, char* dst) {
        int i = t + p * 512;
        if (i < 3616) {
            int row = i >> 2, sl = i & 3;
            int c = sl ^ ((row >> 1) & 3);
            const __hip_bfloat16* src;
            if (row < 384) {
                int jj = row >> 7, col = row & 127;
                src = Aw + (size_t)(co0 + col) * 2304 + (3 * nky + jj) * 256
                         + ncih * 32 + c * 8;
            } else {
                int rbi = row - 384;
                int yl  = rbi / 130;
                int xi  = rbi - 130 * yl;
                int gy  = y0 + nky - 1 + yl, gx = xi - 1;
                src = ((unsigned)gy < 128u && (unsigned)gx < 128u)
                    ? bbase + ((size_t)(gy * 128 + gx)) * 256 + ncih * 32 + c * 8
                    : (const __hip_bfloat16*)((const char*)zbuf + c * 16);
            }
            load16_lds(src, dst + (size_t)i * 16);
        }
    };

    // prologue: fully stage step 0 into buffer 0
#pragma unroll
    for (int p = 0; p < 8; ++p) stage_slot(p, 0, 0, smb);
    __syncthreads();

#pragma unroll 1
    for (int step = 0; step < 24; ++step) {
        const char* cb_ = smb + (size_t)(step & 1) * BUFB;
        char*       nb_ = smb + (size_t)((step + 1) & 1) * BUFB;
        const int nstep = step + 1;
        const int nky = nstep >> 3, ncih = nstep & 7;
        const bool last = (step == 23);

#pragma unroll
        for (int j = 0; j < 3; ++j) {
            bf16x8 af[4], bfv[8];
#pragma unroll
            for (int mt = 0; mt < 4; ++mt) {
                const int ra = j * 128 + mbase + mt * 16 + ml;
                const int sa = q ^ ((ra >> 1) & 3);
                af[mt] = *(const bf16x8*)(cb_ + (size_t)ra * 64 + sa * 16);
            }
#pragma unroll
            for (int nt = 0; nt < 8; ++nt) {
                const int rb = 384 + yy * 130 + nt * 16 + ml + j;
                const int sb = q ^ ((rb >> 1) & 3);
                bfv[nt] = *(const bf16x8*)(cb_ + (size_t)rb * 64 + sb * 16);
            }
            if (!last) {
                const int pbase = j * 3;
                const int pcnt  = (j == 2) ? 2 : 3;
#pragma unroll
                for (int pp = 0; pp < pcnt; ++pp)
                    stage_slot(pbase + pp, nky, ncih, nb_);
            }
            __builtin_amdgcn_s_barrier();
            __builtin_amdgcn_s_setprio(1);
#pragma unroll
            for (int mt = 0; mt < 4; ++mt)
#pragma unroll
                for (int nt = 0; nt < 8; ++nt)
                    acc[mt][nt] = __builtin_amdgcn_mfma_f32_16x16x32_bf16(
                        af[mt], bfv[nt], acc[mt][nt], 0, 0, 0);
            __builtin_amdgcn_s_setprio(0);
            __builtin_amdgcn_s_barrier();
        }
        __syncthreads();   // drains own prefetch (issued phases ago) + barrier
    }

    // epilogue. C/D: col(x)=ml, row(co)=q*4+r.
    if (MODE == 1 && branch == 0) {
        unsigned* colred = (unsigned*)smb;
#pragma unroll
        for (int k2 = 0; k2 < 32; ++k2) colred[t + k2 * 512] = 0u;
        __syncthreads();
    }

#pragma unroll
    for (int mt = 0; mt < 4; ++mt) {
#pragma unroll
        for (int r = 0; r < 4; ++r) {
            const int cl = mbase + mt * 16 + q * 4 + r;   // local co 0..127
            const float sc = s_sc[cl], sh = s_sh[cl];
            const int co = co0 + cl;
            unsigned rmx = 0u;
#pragma unroll
            for (int nt = 0; nt < 8; ++nt) {
                float va = fmaxf(acc[mt][nt][r] * sc + sh, 0.f);
                const int x = nt * 16 + ml;
                if (MODE == 0) {
                    out0[(((size_t)b * CO + co) * HS + y0 + yy) * WS + x] = va;
                } else if (branch == 0) {
                    atomicMax(((unsigned*)smb) + cl * 128 + x, __float_as_uint(va));
                } else {
                    rmx = max(rmx, __float_as_uint(va));
                }
            }
            if (MODE == 1 && branch == 1) atomicMax(&s_red[yy][cl], rmx);
        }
    }

    if (MODE == 1) {
        __syncthreads();
        if (branch == 0) {
            unsigned* colred = (unsigned*)smb;
#pragma unroll
            for (int k2 = 0; k2 < 32; ++k2) {
                int idx = t + k2 * 512;
                atomicMax(cmax + ((size_t)(b * 128 + (idx >> 7))) * 128 + (idx & 127),
                          colred[idx]);
            }
        } else {
            atomicMax(rmax + ((size_t)(b * 128 + (t & 127))) * 128 + y0 + (t >> 7),
                      s_red[t >> 7][t & 127]);
        }
    }
}

// ---------------------------------------------------------------------------
// K3: 1-D decomposition of the merge conv -> U,V (bf16 out).
__global__ __launch_bounds__(128) void k_uv(
    const float* __restrict__ pw, const float* __restrict__ cm,
    const float* __restrict__ rm,
    __hip_bfloat16* __restrict__ U, __hip_bfloat16* __restrict__ V)
{
    const int co   = blockIdx.x;
    const int b    = blockIdx.y;
    const int mode = blockIdx.z;
    const int p    = threadIdx.x;
    float acc0 = 0.f, acc1 = 0.f, acc2 = 0.f;
    const float* base = (mode == 0) ? cm : rm;
    for (int ci = 0; ci < CMID; ++ci) {
        const float* w9 = pw + (co * CMID + ci) * 9;
        float s0[3], s1[3], s2[3];
        if (mode == 0) {
#pragma unroll
            for (int k = 0; k < 3; ++k) {
                float a = w9[k], qq = w9[3 + k], r = w9[6 + k];
                s0[k] = qq + r; s1[k] = a + qq + r; s2[k] = a + qq;
            }
        } else {
#pragma unroll
            for (int k = 0; k < 3; ++k) {
                float a = w9[k*3 + 0], qq = w9[k*3 + 1], r = w9[k*3 + 2];
                s0[k] = qq + r; s1[k] = a + qq + r; s2[k] = a + qq;
            }
        }
        const float* v = base + (b * CMID + ci) * 128;
#pragma unroll
        for (int k = 0; k < 3; ++k) {
            int pos = p + k - 1;
            if ((unsigned)pos < 128u) {
                float vv = v[pos];
                acc0 += s0[k] * vv; acc1 += s1[k] * vv; acc2 += s2[k] * vv;
            }
        }
    }
    __hip_bfloat16* dst = (mode == 0) ? U : V;
    dst[((0 * NB + b) * CDIM + co) * 128 + p] = __float2bfloat16(acc0);
    dst[((1 * NB + b) * CDIM + co) * 128 + p] = __float2bfloat16(acc1);
    dst[((2 * NB + b) * CDIM + co) * 128 + p] = __float2bfloat16(acc2);
}

// ---------------------------------------------------------------------------
// K4 v2: merge as MFMA GEMM, 256co x 128x per block (one y row), 4 waves,
// wave = 64co x 128x (acc 4x8). 128B LDS rows, slot = c ^ (row&7) swizzle.
// Rc[b][y][x][co] = relu(psc*(U+V)+psh + csc*conv1x1+csh), bf16.
__global__ __launch_bounds__(256, 2) void k_merge_mfma(
    const __hip_bfloat16* __restrict__ Xc, const __hip_bfloat16* __restrict__ Aw4,
    const __hip_bfloat16* __restrict__ U, const __hip_bfloat16* __restrict__ V,
    const float* __restrict__ pg, const float* __restrict__ pb,
    const float* __restrict__ pm, const float* __restrict__ pv,
    const float* __restrict__ cg, const float* __restrict__ cb,
    const float* __restrict__ cmn, const float* __restrict__ cv,
    __hip_bfloat16* __restrict__ Rc)
{
    const int y = blockIdx.x;
    const int b = blockIdx.y;
    __shared__ __hip_bfloat16 smem[32768];   // 64 KB: GEMM staging, then U tiles
    __shared__ float s_psc[256], s_psh[256], s_csc[256], s_csh[256];
    __shared__ float s_v0[256], s_vm[256], s_v1[256];
    char* smb = (char*)smem;
    const int t = threadIdx.x, lane = t & 63, w = t >> 6;
    const int ml = lane & 15, q = lane >> 4;
    const int mbase = w * 64;                // wave's co offset
    const int yc = (y == 0) ? 0 : ((y == HS - 1) ? 2 : 1);

    {   // 256 threads cover 256 co
        int co = t;
        float iv = rsqrtf(pv[co] + EPS);
        float psc = pg[co] * iv;
        s_psc[co] = psc;
        s_psh[co] = pb[co] - pm[co] * psc;
        float iv2 = rsqrtf(cv[co] + EPS);
        float csc = cg[co] * iv2;
        s_csc[co] = csc;
        s_csh[co] = cb[co] - cmn[co] * csc;
        const size_t vb = ((size_t)b * CDIM + co) * 128 + y;
        const size_t cstr = (size_t)NB * CDIM * 128;
        s_v0[co] = __bfloat162float(V[vb]);
        s_vm[co] = __bfloat162float(V[cstr + vb]);
        s_v1[co] = __bfloat162float(V[2 * cstr + vb]);
    }

    f32x4 acc[4][8];
#pragma unroll
    for (int mt = 0; mt < 4; ++mt)
#pragma unroll
        for (int nt = 0; nt < 8; ++nt)
            acc[mt][nt] = (f32x4){0.f, 0.f, 0.f, 0.f};

    const __hip_bfloat16* brow = Xc + (size_t)(b * 128 + y) * 128 * 256;
#pragma unroll 1
    for (int ks = 0; ks < 4; ++ks) {
        // stage 384 rows x 128B: A rows 0..255 (co), B rows 256..383 (x)
#pragma unroll
        for (int p = 0; p < 12; ++p) {
            int i   = t + p * 256;           // 0..3071
            int row = i >> 3, sl = i & 7;
            int c   = sl ^ (row & 7);
            const __hip_bfloat16* src = (row < 256)
                ? Aw4 + (size_t)row * 256 + ks * 64 + c * 8
                : brow + (size_t)(row - 256) * 256 + ks * 64 + c * 8;
            load16_lds(src, smb + (size_t)i * 16);
        }
        __syncthreads();
#pragma unroll
        for (int s = 0; s < 2; ++s) {
            bf16x8 af[4], bfv[8];
#pragma unroll
            for (int mt = 0; mt < 4; ++mt) {
                const int ra = mbase + mt * 16 + ml;
                const int coff = ((s * 4 + q) ^ (ra & 7)) * 16;
                af[mt] = *(const bf16x8*)(smb + (size_t)ra * 128 + coff);
            }
#pragma unroll
            for (int nt = 0; nt < 8; ++nt) {
                const int rb = 256 + nt * 16 + ml;
                const int coff = ((s * 4 + q) ^ (rb & 7)) * 16;
                bfv[nt] = *(const bf16x8*)(smb + (size_t)rb * 128 + coff);
            }
#pragma unroll
            for (int mt = 0; mt < 4; ++mt)
#pragma unroll
                for (int nt = 0; nt < 8; ++nt)
                    acc[mt][nt] = __builtin_amdgcn_mfma_f32_16x16x32_bf16(
                        af[mt], bfv[nt], acc[mt][nt], 0, 0, 0);
        }
        __syncthreads();
    }

    // per-wave U stage: 64co x 128x bf16 = 16 KB at wave offset (contiguous)
    const __hip_bfloat16* Ub = U + ((size_t)(yc * NB + b) * CDIM + mbase) * 128;
#pragma unroll
    for (int k = 0; k < 16; ++k) {
        int i = lane + k * 64;
        load16_lds(Ub + (size_t)i * 8, smb + (size_t)w * 16384 + (size_t)i * 16);
    }
    __syncthreads();
    const __hip_bfloat16* ulds = smem + w * 8192;

#pragma unroll
    for (int mt = 0; mt < 4; ++mt) {
#pragma unroll
        for (int nt = 0; nt < 8; ++nt) {
            const int x = nt * 16 + ml;
            unsigned long long pk = 0;
#pragma unroll
            for (int r = 0; r < 4; ++r) {
                const int cl = mt * 16 + q * 4 + r;       // local co in wave
                const int co = mbase + cl;
                float u  = __bfloat162float(ulds[cl * 128 + x]);
                float vt = (x == 0) ? s_v0[co] : ((x == WS - 1) ? s_v1[co] : s_vm[co]);
                float val = fmaxf((u + vt) * s_psc[co] + s_psh[co]
                                  + acc[mt][nt][r] * s_csc[co] + s_csh[co], 0.f);
                __hip_bfloat16 hb = __float2bfloat16(val);
                unsigned short bits;
                __builtin_memcpy(&bits, &hb, 2);
                pk |= (unsigned long long)bits << (16 * r);
            }
            *(unsigned long long*)((char*)Rc +
                ((size_t)((b * 128 + y) * 128 + x) * 256 + mbase + mt * 16 + q * 4) * 2) = pk;
        }
    }
}

// ---------------------------------------------------------------------------
extern "C" void kernel_launch(void* const* d_in, const int* in_sizes, int n_in,
                              void* d_out, int out_size, void* d_ws, size_t ws_size,
                              hipStream_t stream)
{
    (void)in_sizes; (void)n_in; (void)out_size; (void)ws_size;
    const float* x    = (const float*)d_in[0];
    const float* p1_w = (const float*)d_in[1];
    const float* p1_g = (const float*)d_in[2];
    const float* p1_b = (const float*)d_in[3];
    const float* p1_m = (const float*)d_in[4];
    const float* p1_v = (const float*)d_in[5];
    const float* p2_w = (const float*)d_in[6];
    const float* p2_g = (const float*)d_in[7];
    const float* p2_b = (const float*)d_in[8];
    const float* p2_m = (const float*)d_in[9];
    const float* p2_v = (const float*)d_in[10];
    const float* p_w  = (const float*)d_in[11];
    const float* p_g  = (const float*)d_in[12];
    const float* p_b  = (const float*)d_in[13];
    const float* p_m  = (const float*)d_in[14];
    const float* p_v  = (const float*)d_in[15];
    const float* c1_w = (const float*)d_in[16];
    const float* c1_g = (const float*)d_in[17];
    const float* c1_b = (const float*)d_in[18];
    const float* c1_m = (const float*)d_in[19];
    const float* c1_v = (const float*)d_in[20];
    const float* c2_w = (const float*)d_in[21];
    const float* c2_g = (const float*)d_in[22];
    const float* c2_b = (const float*)d_in[23];
    const float* c2_m = (const float*)d_in[24];
    const float* c2_v = (const float*)d_in[25];
    float* out = (float*)d_out;
    char* ws = (char*)d_ws;

    // layout (bytes), total 70,516,992 (<= proven-safe 70,778,880):
    //   Xc @0 (33,554,432) | Rc @33,554,432 (33,554,432)
    //   U @67,108,864 / V @67,895,296 (alias Aw1 @67,108,864, Aw2 @67,698,688)
    //   Aw5 @68,681,728 | Aw4 @69,861,376
    //   zero region @69,992,448 (524,544): cmaxU | rmaxU @70,254,592 | zbuf @70,516,736
    __hip_bfloat16* Xc   = (__hip_bfloat16*)ws;
    __hip_bfloat16* Rc   = (__hip_bfloat16*)(ws + 33554432);
    __hip_bfloat16* Ubuf = (__hip_bfloat16*)(ws + 67108864);
    __hip_bfloat16* Vbuf = (__hip_bfloat16*)(ws + 67895296);
    __hip_bfloat16* Aw1  = (__hip_bfloat16*)(ws + 67108864);
    __hip_bfloat16* Aw2  = (__hip_bfloat16*)(ws + 67698688);
    __hip_bfloat16* Aw5  = (__hip_bfloat16*)(ws + 68681728);
    __hip_bfloat16* Aw4  = (__hip_bfloat16*)(ws + 69861376);
    unsigned*       cmaxU = (unsigned*)(ws + 69992448);
    unsigned*       rmaxU = (unsigned*)(ws + 70254592);
    float*          zbuf  = (float*)(ws + 70516736);

    k_wprep_all<<<dim3(769), 256, 0, stream>>>(
        p1_w, p2_w, c2_w, c1_w, Aw1, Aw2, Aw5, Aw4, (f32x4*)(ws + 69992448));
    k_xprep<<<dim3(128, 4), 512, 0, stream>>>(x, Xc);

    // fused K1+K2: blockIdx.y = branch (0: colmax/Aw1, 1: rowmax/Aw2)
    k_conv3<1><<<dim3(32, 2, 4), 512, 0, stream>>>(
        Xc, Aw1, Aw2, zbuf,
        p1_g, p1_b, p1_m, p1_v, p2_g, p2_b, p2_m, p2_v,
        nullptr, cmaxU, rmaxU, CMID);

    k_uv<<<dim3(256, 4, 2), 128, 0, stream>>>(
        p_w, (const float*)cmaxU, (const float*)rmaxU, Ubuf, Vbuf);

    k_merge_mfma<<<dim3(128, 4), 256, 0, stream>>>(
        Xc, Aw4, Ubuf, Vbuf, p_g, p_b, p_m, p_v,
        c1_g, c1_b, c1_m, c1_v, Rc);

    // K5: blockIdx.y = co-tile
    k_conv3<0><<<dim3(32, 2, 4), 512, 0, stream>>>(
        Rc, Aw5, nullptr, zbuf,
        c2_g, c2_b, c2_m, c2_v, nullptr, nullptr, nullptr, nullptr,
        out, nullptr, nullptr, CDIM);
}

// Round 2
// 388.272 us; speedup vs baseline: 1.0231x; 1.0231x over previous
//
#include <hip/hip_runtime.h>
#include <hip/hip_bf16.h>
#include <math.h>

// pool_cross on MI355X — round 9.
// k_conv3: derived-waits counted-vmcnt pipeline (T3+T4 proper port).
//   - block = 4 y-rows x 128co x 128x, 512 thr, 8 waves, 1 block/CU
//   - LDS dbuf 2 x 57,344 B; staging = exactly 7 uniform slots of 512
//     16B-chunks per step (B 4 slots + A 3 slots). B tile is 128 cols
//     (no x-halo); x-edge taps handled by per-lane zero-select on the
//     B fragment (only x==0 @ kx=0 and x==127 @ kx=2 lanes).
//   - NO __syncthreads in the K-loop. Per phase: s_waitcnt vmcnt(N) +
//     raw s_barrier with derived N: issue order per step B3 B4 B5 | B6 A0
//     | A1 A2 interleaved into the 3 kx phases; steady-state waits
//     2/4/5, peeled last step 2/1/0. Every load gets ~3 MFMA phases
//     (~3.7 kcyc) of latency cover vs HBM ~900 cyc.
//   - round-8 failure diagnosed: per-step __syncthreads = vmcnt(0) drain
//     every step (the T4 anti-pattern) + loss of cross-block overlap.
// Other kernels unchanged.
//
// pool algebra (verified): bottom(top(a)) = colmax bcast, right(left(a)) =
// rowmax bcast; merge conv input is rank-1 -> 1-D k_uv decomposition.
// Pool maxes via atomicMax on fp32 bits (valid: values >= 0 post-relu).

constexpr int NB   = 4;
constexpr int CDIM = 256;
constexpr int CMID = 128;
constexpr int HS   = 128;
constexpr int WS   = 128;
constexpr float EPS = 1e-5f;

typedef __bf16 bf16x8 __attribute__((ext_vector_type(8)));
typedef float  f32x4  __attribute__((ext_vector_type(4)));

#define AS1 __attribute__((address_space(1)))
#define AS3 __attribute__((address_space(3)))

__device__ __forceinline__ void load16_lds(const void* gsrc, void* ldst) {
    __builtin_amdgcn_global_load_lds((const AS1 unsigned int*)gsrc,
                                     (AS3 unsigned int*)ldst, 16, 0, 0);
}

// ---------------------------------------------------------------------------
// P0: x[b][ci][y][x] fp32 -> Xc[b][y][x][ci] bf16. Single pass, 512 threads.
__global__ __launch_bounds__(512) void k_xprep(const float* __restrict__ xin,
                                               __hip_bfloat16* __restrict__ Xc)
{
    const int y = blockIdx.x;
    const int b = blockIdx.y;
    const int t = threadIdx.x;
    __shared__ __hip_bfloat16 lds[128 * 264];   // [x][ci], ci-dim padded to 264
#pragma unroll
    for (int k = 0; k < 16; ++k) {
        int idx = t + k * 512;            // 0..8191
        int ci = idx >> 5, x4 = idx & 31;
        f32x4 v = *(const f32x4*)(xin + (((size_t)b * CDIM + ci) * HS + y) * WS + x4 * 4);
#pragma unroll
        for (int j = 0; j < 4; ++j)
            lds[(x4 * 4 + j) * 264 + ci] = __float2bfloat16(v[j]);
    }
    __syncthreads();
#pragma unroll
    for (int k = 0; k < 8; ++k) {
        int i = t + k * 512;              // 0..4095 chunks of 16B
        int x = i >> 5, c8 = i & 31;
        bf16x8 vv = *(const bf16x8*)(lds + x * 264 + c8 * 8);
        *(bf16x8*)(Xc + ((size_t)(b * 128 + y) * 128 + x) * 256 + c8 * 8) = vv;
    }
}

// ---------------------------------------------------------------------------
// All weight preps + zero-fill in one kernel.
// bid 0..127: Aw1; 128..255: Aw2; 256..511: Aw5; 512..639: Aw4 (1x1);
// bid 640..767: zero 4KB each of the cmax|rmax|zbuf region; 768: tail 256B.
__global__ __launch_bounds__(256) void k_wprep_all(
    const float* __restrict__ p1w, const float* __restrict__ p2w,
    const float* __restrict__ c2w, const float* __restrict__ c1w,
    __hip_bfloat16* __restrict__ Aw1, __hip_bfloat16* __restrict__ Aw2,
    __hip_bfloat16* __restrict__ Aw5, __hip_bfloat16* __restrict__ Aw4,
    f32x4* __restrict__ zdst)
{
    const int bid = blockIdx.x;
    const int t   = threadIdx.x;
    if (bid < 512) {
        const float* W; __hip_bfloat16* A; int co;
        if (bid < 128)      { W = p1w; A = Aw1; co = bid; }
        else if (bid < 256) { W = p2w; A = Aw2; co = bid - 128; }
        else                { W = c2w; A = Aw5; co = bid - 256; }
#pragma unroll
        for (int tap = 0; tap < 9; ++tap)
            A[(size_t)co * 2304 + tap * 256 + t] =
                __float2bfloat16(W[((size_t)co * CDIM + t) * 9 + tap]);
    } else if (bid < 640) {
        int base = (bid - 512) * 512 + t;
        Aw4[base]       = __float2bfloat16(c1w[base]);
        Aw4[base + 256] = __float2bfloat16(c1w[base + 256]);
    } else if (bid < 768) {
        zdst[(size_t)(bid - 640) * 256 + t] = (f32x4){0.f, 0.f, 0.f, 0.f};
    } else {
        if (t < 16) zdst[32768 + t] = (f32x4){0.f, 0.f, 0.f, 0.f};
    }
}

// ---------------------------------------------------------------------------
// Conv3x3 implicit GEMM v4: counted-vmcnt double-buffered pipeline.
// Staging layout per buffer (896 rows x 64B, chunk = row*4+slot, logical
// chunk c = slot ^ ((row>>1)&3)):
//   rows 0..383   : A, kx-major: row = kx*128 + co_col  (slots p=0,1,2)
//   rows 384..895 : B: row = 384 + yl*128 + x           (slots p=3..6)
// Per-thread slot constants: col = t>>2, swizzled chunk cc = (t&3)^((t>>3)&3).
// MODE 0: plain fp32 NCHW store (K5, blockIdx.y = co-tile). MODE 1: fused
// branches: blockIdx.y==0 -> colmax (LDS colred fold + atomics), ==1 ->
// rowmax (LDS s_red fold + atomics).
template<int MODE>
__global__ __launch_bounds__(512, 2) void k_conv3(
    const __hip_bfloat16* __restrict__ Xc,
    const __hip_bfloat16* __restrict__ AwA, const __hip_bfloat16* __restrict__ AwB,
    const float* __restrict__ zbuf,
    const float* __restrict__ g1, const float* __restrict__ b1,
    const float* __restrict__ m1, const float* __restrict__ v1,
    const float* __restrict__ g2, const float* __restrict__ b2,
    const float* __restrict__ m2, const float* __restrict__ v2,
    float* __restrict__ out0, unsigned* __restrict__ cmax,
    unsigned* __restrict__ rmax, int CO)
{
    const int y0     = blockIdx.x * 4;
    const int branch = blockIdx.y;              // MODE1: branch; MODE0: co-tile
    const int b      = blockIdx.z;
    const int co0    = (MODE == 0) ? branch * 128 : 0;

    const __hip_bfloat16* Aw = (MODE == 1 && branch) ? AwB : AwA;
    const float* gg  = (MODE == 1 && branch) ? g2 : g1;
    const float* bbp = (MODE == 1 && branch) ? b2 : b1;
    const float* mmp = (MODE == 1 && branch) ? m2 : m1;
    const float* vvp = (MODE == 1 && branch) ? v2 : v1;

    constexpr int BUFB = 896 * 64;              // 57,344 B per buffer
    __shared__ alignas(16) char smb[2 * BUFB];  // 114,688 B
    __shared__ float s_sc[128], s_sh[128];
    __shared__ unsigned s_red[4][128];

    const int t    = threadIdx.x;
    const int lane = t & 63;
    const int w    = t >> 6;
    const int ml   = lane & 15;
    const int q    = lane >> 4;
    const int yy    = w >> 1;                   // wave's y-row 0..3
    const int mbase = (w & 1) * 64;             // wave's co half

    // per-thread staging constants (slot-invariant, see header comment)
    const int cc  = (t & 3) ^ ((t >> 3) & 3);
    const int col = t >> 2;

    if (t < 128) {
        int co = co0 + t;
        float iv = rsqrtf(vvp[co] + EPS);
        float sc = gg[co] * iv;
        s_sc[t] = sc;
        s_sh[t] = bbp[co] - mmp[co] * sc;
    }
    if (MODE == 1 && branch == 1) ((unsigned*)s_red)[t] = 0u;

    f32x4 acc[4][8];
#pragma unroll
    for (int mt = 0; mt < 4; ++mt)
#pragma unroll
        for (int nt = 0; nt < 8; ++nt)
            acc[mt][nt] = (f32x4){0.f, 0.f, 0.f, 0.f};

    const __hip_bfloat16* bbase = Xc + (size_t)(b * 128) * 128 * 256;
    const char* zrow = (const char*)zbuf + cc * 16;

    auto stage_A = [&](char* dst, int p, int nky, int ncih) {
        const __hip_bfloat16* src = Aw + (size_t)(co0 + col) * 2304
            + (3 * nky + p) * 256 + ncih * 32 + cc * 8;
        load16_lds(src, dst + (size_t)(t + p * 512) * 16);
    };
    auto stage_B = [&](char* dst, int p, int nky, int ncih) {
        const int gy = y0 + nky - 1 + (p - 3);
        const __hip_bfloat16* src = ((unsigned)gy < 128u)
            ? bbase + ((size_t)(gy * 128 + col)) * 256 + ncih * 32 + cc * 8
            : (const __hip_bfloat16*)zrow;
        load16_lds(src, dst + (size_t)(t + p * 512) * 16);
    };

    bf16x8 BZERO;
#pragma unroll
    for (int k = 0; k < 8; ++k) BZERO[k] = (__bf16)0.0f;

    // prologue: batch 0, fixed issue order B3 B4 B5 B6 A0 A1 A2
    stage_B(smb, 3, 0, 0); stage_B(smb, 4, 0, 0); stage_B(smb, 5, 0, 0);
    stage_B(smb, 6, 0, 0);
    stage_A(smb, 0, 0, 0); stage_A(smb, 1, 0, 0); stage_A(smb, 2, 0, 0);

#define WAITB(N) \
    asm volatile("s_waitcnt vmcnt(" #N ")" ::: "memory"); \
    __builtin_amdgcn_s_barrier(); \
    __builtin_amdgcn_sched_barrier(0);

#define DS_PHASE(J, CB) \
    bf16x8 af[4], bfv[8]; \
    { \
        _Pragma("unroll") \
        for (int mt = 0; mt < 4; ++mt) { \
            const int ra = (J) * 128 + mbase + mt * 16 + ml; \
            const int sa = q ^ ((ra >> 1) & 3); \
            af[mt] = *(const bf16x8*)((CB) + (size_t)ra * 64 + sa * 16); \
        } \
        _Pragma("unroll") \
        for (int nt = 0; nt < 8; ++nt) { \
            const int rbl = nt * 16 + ml + (J) - 1; \
            const int rbc = rbl < 0 ? 0 : (rbl > 127 ? 127 : rbl); \
            const int rb  = 384 + yy * 128 + rbc; \
            const int sb  = q ^ ((rb >> 1) & 3); \
            bf16x8 bv = *(const bf16x8*)((CB) + (size_t)rb * 64 + sb * 16); \
            bfv[nt] = ((unsigned)rbl < 128u) ? bv : BZERO; \
        } \
    }

#define MFMA_PHASE() \
    __builtin_amdgcn_s_setprio(1); \
    _Pragma("unroll") \
    for (int mt = 0; mt < 4; ++mt) \
        _Pragma("unroll") \
        for (int nt = 0; nt < 8; ++nt) \
            acc[mt][nt] = __builtin_amdgcn_mfma_f32_16x16x32_bf16( \
                af[mt], bfv[nt], acc[mt][nt], 0, 0, 0); \
    __builtin_amdgcn_s_setprio(0);

#pragma unroll 1
    for (int step = 0; step < 23; ++step) {
        const char* cb_ = smb + (size_t)(step & 1) * BUFB;
        char*       nb_ = smb + (size_t)((step + 1) & 1) * BUFB;
        const int nstep = step + 1;
        const int nky = nstep >> 3, ncih = nstep & 7;
        {
            WAITB(2)
            DS_PHASE(0, cb_)
            stage_B(nb_, 3, nky, ncih);
            stage_B(nb_, 4, nky, ncih);
            stage_B(nb_, 5, nky, ncih);
            MFMA_PHASE()
        }
        {
            WAITB(4)
            DS_PHASE(1, cb_)
            stage_B(nb_, 6, nky, ncih);
            stage_A(nb_, 0, nky, ncih);
            MFMA_PHASE()
        }
        {
            WAITB(5)
            DS_PHASE(2, cb_)
            stage_A(nb_, 1, nky, ncih);
            stage_A(nb_, 2, nky, ncih);
            MFMA_PHASE()
        }
    }
    {   // peeled step 23: buffer 1, no staging, drain waits 2/1/0
        const char* cb_ = smb + BUFB;
        { WAITB(2) DS_PHASE(0, cb_) MFMA_PHASE() }
        { WAITB(1) DS_PHASE(1, cb_) MFMA_PHASE() }
        { WAITB(0) DS_PHASE(2, cb_) MFMA_PHASE() }
    }
#undef WAITB
#undef DS_PHASE
#undef MFMA_PHASE

    // epilogue. C/D: col(x)=ml, row(co)=q*4+r.
    if (MODE == 1 && branch == 0) {
        // colred (64KB) spans buffer0 + first 8KB of buffer1 (rows 0..127 =
        // A kx0, last read at step-23 phase 0 — all waves past ph2 barrier).
        unsigned* colred = (unsigned*)smb;
#pragma unroll
        for (int k2 = 0; k2 < 32; ++k2) colred[t + k2 * 512] = 0u;
        __syncthreads();
    }

#pragma unroll
    for (int mt = 0; mt < 4; ++mt) {
#pragma unroll
        for (int r = 0; r < 4; ++r) {
            const int cl = mbase + mt * 16 + q * 4 + r;   // local co 0..127
            const float sc = s_sc[cl], sh = s_sh[cl];
            const int co = co0 + cl;
            unsigned rmx = 0u;
#pragma unroll
            for (int nt = 0; nt < 8; ++nt) {
                float va = fmaxf(acc[mt][nt][r] * sc + sh, 0.f);
                const int x = nt * 16 + ml;
                if (MODE == 0) {
                    out0[(((size_t)b * CO + co) * HS + y0 + yy) * WS + x] = va;
                } else if (branch == 0) {
                    atomicMax(((unsigned*)smb) + cl * 128 + x, __float_as_uint(va));
                } else {
                    rmx = max(rmx, __float_as_uint(va));
                }
            }
            if (MODE == 1 && branch == 1) atomicMax(&s_red[yy][cl], rmx);
        }
    }

    if (MODE == 1) {
        __syncthreads();
        if (branch == 0) {
            unsigned* colred = (unsigned*)smb;
#pragma unroll
            for (int k2 = 0; k2 < 32; ++k2) {
                int idx = t + k2 * 512;
                atomicMax(cmax + ((size_t)(b * 128 + (idx >> 7))) * 128 + (idx & 127),
                          colred[idx]);
            }
        } else {
            atomicMax(rmax + ((size_t)(b * 128 + (t & 127))) * 128 + y0 + (t >> 7),
                      s_red[t >> 7][t & 127]);
        }
    }
}

// ---------------------------------------------------------------------------
// K3: 1-D decomposition of the merge conv -> U,V (bf16 out).
__global__ __launch_bounds__(128) void k_uv(
    const float* __restrict__ pw, const float* __restrict__ cm,
    const float* __restrict__ rm,
    __hip_bfloat16* __restrict__ U, __hip_bfloat16* __restrict__ V)
{
    const int co   = blockIdx.x;
    const int b    = blockIdx.y;
    const int mode = blockIdx.z;
    const int p    = threadIdx.x;
    float acc0 = 0.f, acc1 = 0.f, acc2 = 0.f;
    const float* base = (mode == 0) ? cm : rm;
    for (int ci = 0; ci < CMID; ++ci) {
        const float* w9 = pw + (co * CMID + ci) * 9;
        float s0[3], s1[3], s2[3];
        if (mode == 0) {
#pragma unroll
            for (int k = 0; k < 3; ++k) {
                float a = w9[k], qq = w9[3 + k], r = w9[6 + k];
                s0[k] = qq + r; s1[k] = a + qq + r; s2[k] = a + qq;
            }
        } else {
#pragma unroll
            for (int k = 0; k < 3; ++k) {
                float a = w9[k*3 + 0], qq = w9[k*3 + 1], r = w9[k*3 + 2];
                s0[k] = qq + r; s1[k] = a + qq + r; s2[k] = a + qq;
            }
        }
        const float* v = base + (b * CMID + ci) * 128;
#pragma unroll
        for (int k = 0; k < 3; ++k) {
            int pos = p + k - 1;
            if ((unsigned)pos < 128u) {
                float vv = v[pos];
                acc0 += s0[k] * vv; acc1 += s1[k] * vv; acc2 += s2[k] * vv;
            }
        }
    }
    __hip_bfloat16* dst = (mode == 0) ? U : V;
    dst[((0 * NB + b) * CDIM + co) * 128 + p] = __float2bfloat16(acc0);
    dst[((1 * NB + b) * CDIM + co) * 128 + p] = __float2bfloat16(acc1);
    dst[((2 * NB + b) * CDIM + co) * 128 + p] = __float2bfloat16(acc2);
}

// ---------------------------------------------------------------------------
// K4 v2: merge as MFMA GEMM, 256co x 128x per block (one y row), 4 waves,
// wave = 64co x 128x (acc 4x8). 128B LDS rows, slot = c ^ (row&7) swizzle.
// Rc[b][y][x][co] = relu(psc*(U+V)+psh + csc*conv1x1+csh), bf16.
__global__ __launch_bounds__(256, 2) void k_merge_mfma(
    const __hip_bfloat16* __restrict__ Xc, const __hip_bfloat16* __restrict__ Aw4,
    const __hip_bfloat16* __restrict__ U, const __hip_bfloat16* __restrict__ V,
    const float* __restrict__ pg, const float* __restrict__ pb,
    const float* __restrict__ pm, const float* __restrict__ pv,
    const float* __restrict__ cg, const float* __restrict__ cb,
    const float* __restrict__ cmn, const float* __restrict__ cv,
    __hip_bfloat16* __restrict__ Rc)
{
    const int y = blockIdx.x;
    const int b = blockIdx.y;
    __shared__ __hip_bfloat16 smem[32768];   // 64 KB: GEMM staging, then U tiles
    __shared__ float s_psc[256], s_psh[256], s_csc[256], s_csh[256];
    __shared__ float s_v0[256], s_vm[256], s_v1[256];
    char* smb = (char*)smem;
    const int t = threadIdx.x, lane = t & 63, w = t >> 6;
    const int ml = lane & 15, q = lane >> 4;
    const int mbase = w * 64;                // wave's co offset
    const int yc = (y == 0) ? 0 : ((y == HS - 1) ? 2 : 1);

    {   // 256 threads cover 256 co
        int co = t;
        float iv = rsqrtf(pv[co] + EPS);
        float psc = pg[co] * iv;
        s_psc[co] = psc;
        s_psh[co] = pb[co] - pm[co] * psc;
        float iv2 = rsqrtf(cv[co] + EPS);
        float csc = cg[co] * iv2;
        s_csc[co] = csc;
        s_csh[co] = cb[co] - cmn[co] * csc;
        const size_t vb = ((size_t)b * CDIM + co) * 128 + y;
        const size_t cstr = (size_t)NB * CDIM * 128;
        s_v0[co] = __bfloat162float(V[vb]);
        s_vm[co] = __bfloat162float(V[cstr + vb]);
        s_v1[co] = __bfloat162float(V[2 * cstr + vb]);
    }

    f32x4 acc[4][8];
#pragma unroll
    for (int mt = 0; mt < 4; ++mt)
#pragma unroll
        for (int nt = 0; nt < 8; ++nt)
            acc[mt][nt] = (f32x4){0.f, 0.f, 0.f, 0.f};

    const __hip_bfloat16* brow = Xc + (size_t)(b * 128 + y) * 128 * 256;
#pragma unroll 1
    for (int ks = 0; ks < 4; ++ks) {
        // stage 384 rows x 128B: A rows 0..255 (co), B rows 256..383 (x)
#pragma unroll
        for (int p = 0; p < 12; ++p) {
            int i   = t + p * 256;           // 0..3071
            int row = i >> 3, sl = i & 7;
            int c   = sl ^ (row & 7);
            const __hip_bfloat16* src = (row < 256)
                ? Aw4 + (size_t)row * 256 + ks * 64 + c * 8
                : brow + (size_t)(row - 256) * 256 + ks * 64 + c * 8;
            load16_lds(src, smb + (size_t)i * 16);
        }
        __syncthreads();
#pragma unroll
        for (int s = 0; s < 2; ++s) {
            bf16x8 af[4], bfv[8];
#pragma unroll
            for (int mt = 0; mt < 4; ++mt) {
                const int ra = mbase + mt * 16 + ml;
                const int coff = ((s * 4 + q) ^ (ra & 7)) * 16;
                af[mt] = *(const bf16x8*)(smb + (size_t)ra * 128 + coff);
            }
#pragma unroll
            for (int nt = 0; nt < 8; ++nt) {
                const int rb = 256 + nt * 16 + ml;
                const int coff = ((s * 4 + q) ^ (rb & 7)) * 16;
                bfv[nt] = *(const bf16x8*)(smb + (size_t)rb * 128 + coff);
            }
#pragma unroll
            for (int mt = 0; mt < 4; ++mt)
#pragma unroll
                for (int nt = 0; nt < 8; ++nt)
                    acc[mt][nt] = __builtin_amdgcn_mfma_f32_16x16x32_bf16(
                        af[mt], bfv[nt], acc[mt][nt], 0, 0, 0);
        }
        __syncthreads();
    }

    // per-wave U stage: 64co x 128x bf16 = 16 KB at wave offset (contiguous)
    const __hip_bfloat16* Ub = U + ((size_t)(yc * NB + b) * CDIM + mbase) * 128;
#pragma unroll
    for (int k = 0; k < 16; ++k) {
        int i = lane + k * 64;
        load16_lds(Ub + (size_t)i * 8, smb + (size_t)w * 16384 + (size_t)i * 16);
    }
    __syncthreads();
    const __hip_bfloat16* ulds = smem + w * 8192;

#pragma unroll
    for (int mt = 0; mt < 4; ++mt) {
#pragma unroll
        for (int nt = 0; nt < 8; ++nt) {
            const int x = nt * 16 + ml;
            unsigned long long pk = 0;
#pragma unroll
            for (int r = 0; r < 4; ++r) {
                const int cl = mt * 16 + q * 4 + r;       // local co in wave
                const int co = mbase + cl;
                float u  = __bfloat162float(ulds[cl * 128 + x]);
                float vt = (x == 0) ? s_v0[co] : ((x == WS - 1) ? s_v1[co] : s_vm[co]);
                float val = fmaxf((u + vt) * s_psc[co] + s_psh[co]
                                  + acc[mt][nt][r] * s_csc[co] + s_csh[co], 0.f);
                __hip_bfloat16 hb = __float2bfloat16(val);
                unsigned short bits;
                __builtin_memcpy(&bits, &hb, 2);
                pk |= (unsigned long long)bits << (16 * r);
            }
            *(unsigned long long*)((char*)Rc +
                ((size_t)((b * 128 + y) * 128 + x) * 256 + mbase + mt * 16 + q * 4) * 2) = pk;
        }
    }
}

// ---------------------------------------------------------------------------
extern "C" void kernel_launch(void* const* d_in, const int* in_sizes, int n_in,
                              void* d_out, int out_size, void* d_ws, size_t ws_size,
                              hipStream_t stream)
{
    (void)in_sizes; (void)n_in; (void)out_size; (void)ws_size;
    const float* x    = (const float*)d_in[0];
    const float* p1_w = (const float*)d_in[1];
    const float* p1_g = (const float*)d_in[2];
    const float* p1_b = (const float*)d_in[3];
    const float* p1_m = (const float*)d_in[4];
    const float* p1_v = (const float*)d_in[5];
    const float* p2_w = (const float*)d_in[6];
    const float* p2_g = (const float*)d_in[7];
    const float* p2_b = (const float*)d_in[8];
    const float* p2_m = (const float*)d_in[9];
    const float* p2_v = (const float*)d_in[10];
    const float* p_w  = (const float*)d_in[11];
    const float* p_g  = (const float*)d_in[12];
    const float* p_b  = (const float*)d_in[13];
    const float* p_m  = (const float*)d_in[14];
    const float* p_v  = (const float*)d_in[15];
    const float* c1_w = (const float*)d_in[16];
    const float* c1_g = (const float*)d_in[17];
    const float* c1_b = (const float*)d_in[18];
    const float* c1_m = (const float*)d_in[19];
    const float* c1_v = (const float*)d_in[20];
    const float* c2_w = (const float*)d_in[21];
    const float* c2_g = (const float*)d_in[22];
    const float* c2_b = (const float*)d_in[23];
    const float* c2_m = (const float*)d_in[24];
    const float* c2_v = (const float*)d_in[25];
    float* out = (float*)d_out;
    char* ws = (char*)d_ws;

    // layout (bytes), total 70,516,992 (<= proven-safe 70,778,880):
    //   Xc @0 (33,554,432) | Rc @33,554,432 (33,554,432)
    //   U @67,108,864 / V @67,895,296 (alias Aw1 @67,108,864, Aw2 @67,698,688)
    //   Aw5 @68,681,728 | Aw4 @69,861,376
    //   zero region @69,992,448 (524,544): cmaxU | rmaxU @70,254,592 | zbuf @70,516,736
    __hip_bfloat16* Xc   = (__hip_bfloat16*)ws;
    __hip_bfloat16* Rc   = (__hip_bfloat16*)(ws + 33554432);
    __hip_bfloat16* Ubuf = (__hip_bfloat16*)(ws + 67108864);
    __hip_bfloat16* Vbuf = (__hip_bfloat16*)(ws + 67895296);
    __hip_bfloat16* Aw1  = (__hip_bfloat16*)(ws + 67108864);
    __hip_bfloat16* Aw2  = (__hip_bfloat16*)(ws + 67698688);
    __hip_bfloat16* Aw5  = (__hip_bfloat16*)(ws + 68681728);
    __hip_bfloat16* Aw4  = (__hip_bfloat16*)(ws + 69861376);
    unsigned*       cmaxU = (unsigned*)(ws + 69992448);
    unsigned*       rmaxU = (unsigned*)(ws + 70254592);
    float*          zbuf  = (float*)(ws + 70516736);

    k_wprep_all<<<dim3(769), 256, 0, stream>>>(
        p1_w, p2_w, c2_w, c1_w, Aw1, Aw2, Aw5, Aw4, (f32x4*)(ws + 69992448));
    k_xprep<<<dim3(128, 4), 512, 0, stream>>>(x, Xc);

    // fused K1+K2: blockIdx.y = branch (0: colmax/Aw1, 1: rowmax/Aw2)
    k_conv3<1><<<dim3(32, 2, 4), 512, 0, stream>>>(
        Xc, Aw1, Aw2, zbuf,
        p1_g, p1_b, p1_m, p1_v, p2_g, p2_b, p2_m, p2_v,
        nullptr, cmaxU, rmaxU, CMID);

    k_uv<<<dim3(256, 4, 2), 128, 0, stream>>>(
        p_w, (const float*)cmaxU, (const float*)rmaxU, Ubuf, Vbuf);

    k_merge_mfma<<<dim3(128, 4), 256, 0, stream>>>(
        Xc, Aw4, Ubuf, Vbuf, p_g, p_b, p_m, p_v,
        c1_g, c1_b, c1_m, c1_v, Rc);

    // K5: blockIdx.y = co-tile
    k_conv3<0><<<dim3(32, 2, 4), 512, 0, stream>>>(
        Rc, Aw5, nullptr, zbuf,
        c2_g, c2_b, c2_m, c2_v, nullptr, nullptr, nullptr, nullptr,
        out, nullptr, nullptr, CDIM);
}